// Round 1
// baseline (244.320 us; speedup 1.0000x reference)
//
#include <hip/hip_runtime.h>

#define E_CONST 3
#define T_CONST 100
#define INV_SIGMA 10.0f
#define ALPHA_C 0.05f

// ---------------------------------------------------------------------------
// Kernel 1: per-(i,s) cumsum over T, write transposed cumT[i][tau][s],
// plus per-(i,k) metadata: v_f, v_b, packed (t, lab).
// One 64-thread block handles 64 consecutive s-rows of one event.
// LDS tile padded to T+1=101 -> lane*101 mod 32 = lane*5 mod 32, conflict-free
// (2-way aliasing for lanes 32..63 is free on gfx950).
// ---------------------------------------------------------------------------
__global__ __launch_bounds__(64) void prep_kernel(
    const float* __restrict__ event_out,  // (E, S, T)
    const int* __restrict__ et,           // (S, E)
    const int* __restrict__ labs,         // (S, E)
    float* __restrict__ cumT,             // (E, T, S)
    float* __restrict__ vfA,              // (E, S)
    float* __restrict__ vbA,              // (E, S)
    int* __restrict__ tlA,                // (E, S) packed t | lab<<16
    int S)
{
    __shared__ float tile[64][T_CONST + 1];
    const int tilesPerEvent = S / 64;
    const int i  = blockIdx.x / tilesPerEvent;
    const int s0 = (blockIdx.x % tilesPerEvent) * 64;
    const int tid = threadIdx.x;

    // coalesced load of 64 rows x 100 cols (rows are contiguous in memory)
    const float* src = event_out + ((size_t)i * S + s0) * T_CONST;
    for (int idx = tid; idx < 64 * T_CONST; idx += 64) {
        int row = idx / T_CONST;
        int col = idx - row * T_CONST;
        tile[row][col] = src[idx];
    }
    __syncthreads();

    // sequential scan of own row (in LDS)
    float run = 0.f;
    for (int tau = 0; tau < T_CONST; ++tau) {
        run += tile[tid][tau];
        tile[tid][tau] = run;
    }
    __syncthreads();

    // transposed, coalesced write: cumT[i][tau][s0+lane]
    float* dst = cumT + (size_t)i * T_CONST * S + s0;
    for (int idx = tid; idx < 64 * T_CONST; idx += 64) {
        int tau = idx >> 6;
        int sl  = idx & 63;
        dst[(size_t)tau * S + sl] = tile[sl][tau];
    }

    // per-k metadata (own row, no extra sync needed for own writes)
    const int s   = s0 + tid;
    const int t   = et[s * E_CONST + i];
    const int lab = labs[s * E_CONST + i];
    const float vf = tile[tid][t];                      // col e_f-1 == t
    const int   cb = lab ? (t > 0 ? t - 1 : 0) : t;     // col max(e_b,1)-1
    const float vb = tile[tid][cb];
    const int base = i * S + s;
    vfA[base] = vf;
    vbA[base] = vb;
    tlA[base] = (t & 0xffff) | (lab << 16);
}

// ---------------------------------------------------------------------------
// Kernel 2: one block per (i,k); 256 threads reduce over all s.
//   forward: lab_k==1, (t_s>t_k || (t_s==t_k && lab_s==0)), v_s>v_k
//            -> exp((v_s - v_k)/sigma)   at column t_k
//   backward: t_k>0, t_s<=cb_k, lab_s==1, v_k>v_s
//            -> exp((v_k - v_s)/sigma)   at column cb_k
// Diagonal (s==k) self-excludes (diff==0 fails strict inequality).
// ---------------------------------------------------------------------------
__global__ __launch_bounds__(256) void pair_kernel(
    const float* __restrict__ cumT,
    const float* __restrict__ vfA,
    const float* __restrict__ vbA,
    const int* __restrict__ tlA,
    float* __restrict__ partials,
    int S)
{
    const int bx = blockIdx.x;
    const int i  = bx / S;
    const int k  = bx - i * S;
    const int base = i * S;

    const int tlk   = tlA[base + k];
    const int t_k   = tlk & 0xffff;
    const int lab_k = tlk >> 16;
    const bool doF = (lab_k == 1);
    const bool doB = (t_k > 0);

    float sum = 0.f;
    if (doF || doB) {
        const float vf_k = vfA[base + k];
        const float vb_k = vbA[base + k];
        const int cb = lab_k ? (t_k > 0 ? t_k - 1 : 0) : t_k;  // == tb_lim when doB
        const float* __restrict__ colF = cumT + ((size_t)i * T_CONST + t_k) * S;
        const float* __restrict__ colB = cumT + ((size_t)i * T_CONST + cb)  * S;
        const int* __restrict__ tlp = tlA + base;

        for (int s = threadIdx.x; s < S; s += 256) {
            const int tls   = tlp[s];
            const int t_s   = tls & 0xffff;
            const int lab_s = tls >> 16;
            if (doF) {
                const float vs = colF[s];
                const bool c = (t_s > t_k) | ((t_s == t_k) & (lab_s == 0));
                if (c & (vs > vf_k)) sum += __expf((vs - vf_k) * INV_SIGMA);
            }
            if (doB) {
                const float vs = colB[s];
                const bool c = (t_s <= cb) & (lab_s == 1);
                if (c & (vb_k > vs)) sum += __expf((vb_k - vs) * INV_SIGMA);
            }
        }
    }

    // block reduction: wave shuffle then cross-wave via LDS
    for (int off = 32; off > 0; off >>= 1) sum += __shfl_down(sum, off, 64);
    __shared__ float wsum[4];
    const int lane = threadIdx.x & 63;
    const int wid  = threadIdx.x >> 6;
    if (lane == 0) wsum[wid] = sum;
    __syncthreads();
    if (threadIdx.x == 0)
        partials[bx] = wsum[0] + wsum[1] + wsum[2] + wsum[3];
}

// ---------------------------------------------------------------------------
// Kernel 3: final reduction of per-block partials -> out[0] = ALPHA * total
// (single writer; no zeroing of d_out needed despite 0xAA poison)
// ---------------------------------------------------------------------------
__global__ __launch_bounds__(256) void reduce_kernel(
    const float* __restrict__ partials, int n, float* __restrict__ out)
{
    float sum = 0.f;
    for (int idx = threadIdx.x; idx < n; idx += 256) sum += partials[idx];
    for (int off = 32; off > 0; off >>= 1) sum += __shfl_down(sum, off, 64);
    __shared__ float wsum[4];
    const int lane = threadIdx.x & 63;
    const int wid  = threadIdx.x >> 6;
    if (lane == 0) wsum[wid] = sum;
    __syncthreads();
    if (threadIdx.x == 0)
        out[0] = ALPHA_C * (wsum[0] + wsum[1] + wsum[2] + wsum[3]);
}

extern "C" void kernel_launch(void* const* d_in, const int* in_sizes, int n_in,
                              void* d_out, int out_size, void* d_ws, size_t ws_size,
                              hipStream_t stream)
{
    const float* event_out = (const float*)d_in[0];  // (E,S,T) fp32
    const int*   et        = (const int*)d_in[1];    // (S,E) int32
    const int*   labsp     = (const int*)d_in[2];    // (S,E) int32
    const int S = in_sizes[1] / E_CONST;             // 8192

    // workspace layout
    float* cumT = (float*)d_ws;                                   // E*T*S floats
    float* vfA  = cumT + (size_t)E_CONST * T_CONST * S;           // E*S
    float* vbA  = vfA + (size_t)E_CONST * S;                      // E*S
    int*   tlA  = (int*)(vbA + (size_t)E_CONST * S);              // E*S
    float* partials = (float*)(tlA + (size_t)E_CONST * S);        // E*S

    const int prepBlocks = E_CONST * (S / 64);
    hipLaunchKernelGGL(prep_kernel, dim3(prepBlocks), dim3(64), 0, stream,
                       event_out, et, labsp, cumT, vfA, vbA, tlA, S);

    const int nB = E_CONST * S;
    hipLaunchKernelGGL(pair_kernel, dim3(nB), dim3(256), 0, stream,
                       cumT, vfA, vbA, tlA, partials, S);

    hipLaunchKernelGGL(reduce_kernel, dim3(1), dim3(256), 0, stream,
                       partials, nB, (float*)d_out);
}